// Round 6
// baseline (331.598 us; speedup 1.0000x reference)
//
#include <hip/hip_runtime.h>

// B=16, C=128, H=256, W=64.  Pipeline:
//  K0: convert wq/wk/wv/wfc fp32->bf16 into ws tail (once per launch)
//  K1: Q/K/V = relu(Wx+b) -> ws [b][n=h*64+w][c] bf16; 16KB half-staged
//      row writes, 48KB LDS -> 3 blocks/CU
//  K2: per-(b,w) attention over H (R5-verified, untouched)
//  K3: out = relu(wfc . att^T + bfc), bf16 weights

typedef __attribute__((ext_vector_type(8))) short short8;
typedef __attribute__((ext_vector_type(4))) float f32x4;

#define MFMA16(acc, a, b) (acc) = __builtin_amdgcn_mfma_f32_16x16x32_bf16((a), (b), (acc), 0, 0, 0)

__device__ __forceinline__ unsigned short f2b(float f) {
  unsigned u = __builtin_bit_cast(unsigned, f);
  u = (u + 0x7fffu + ((u >> 16) & 1u)) >> 16;   // RNE
  return (unsigned short)u;
}

// [R][128c] bf16 tile, row-XOR swizzle (verified write-scalar/read-b128 pair)
__device__ __forceinline__ unsigned adr_s(int r, int c) {
  return (unsigned)(((r << 8) + (c << 1)) ^ ((r & 7) << 4));
}
// K1's XS [128j][128c]: stronger row-hash (rows written in stride-4 bursts)
__device__ __forceinline__ unsigned adr_q(int r, int c) {
  return (unsigned)(((r << 8) + (c << 1)) ^ (((r ^ (r >> 3)) & 7) << 4));
}
// V^T tile [128c][256g] (R5-verified double-XOR)
__device__ __forceinline__ unsigned adr_vt(int c, int g) {
  unsigned blk = (unsigned)(((g >> 3) ^ (c & 7) ^ ((c >> 3) & 7)) & 31);
  return (unsigned)((c << 9) + (blk << 4) + ((g & 7) << 1));
}
// per-wave P quarter-slice [16r][64c] bf16 (2KB), row-hash (R5-verified)
__device__ __forceinline__ unsigned ps_adr(int r, int c) {
  return (unsigned)(((r << 7) + (c << 1)) ^ (((r ^ (r >> 3)) & 7) << 4));
}

__device__ __forceinline__ short8 ldsf(const char* p, unsigned off) {
  return *(const short8*)(p + off);
}

// ================= K0: weight pre-convert fp32 -> bf16 =================
// wb layout: [4 matrices][128 o][128 c] bf16, same row-major as source.
__global__ __launch_bounds__(256) void k0_wcvt(
    const float* __restrict__ wq, const float* __restrict__ wk,
    const float* __restrict__ wv, const float* __restrict__ wfc,
    unsigned short* __restrict__ wb)
{
  int i = blockIdx.x * 256 + threadIdx.x;    // 16384 float4's total
  int mat = i >> 12, off = (i & 4095) * 4;
  const float* src = (mat == 0) ? wq : (mat == 1) ? wk : (mat == 2) ? wv : wfc;
  float4 v = *(const float4*)(src + off);
  uint2 u;
  u.x = (unsigned)f2b(v.x) | ((unsigned)f2b(v.y) << 16);
  u.y = (unsigned)f2b(v.z) | ((unsigned)f2b(v.w) << 16);
  *(uint2*)(wb + mat * 16384 + off) = u;
}

// ================= K1: QKV projection =================
// grid = nbc*128; block tile = 128 n.
// LDS: XS [128n][128c] @0 (32K), WS half-stage [64n][128c] @32K (16K). 48K total.

__device__ __forceinline__ void k1_one(const unsigned short* wmat, const float* bias,
    unsigned short* dst, const char* XS, char* WS,
    int brel, int n0, int wvid, int l, int l16, int g4) {
  const int strip = wvid * 16;
  short8 wf[4];
#pragma unroll
  for (int kk = 0; kk < 4; ++kk)
    wf[kk] = *(const short8*)(wmat + (strip + l16) * 128 + kk * 32 + g4 * 8);
  float bv4[4];
#pragma unroll
  for (int r = 0; r < 4; ++r) bv4[r] = bias[strip + g4 * 4 + r];

  f32x4 acc[8];
#pragma unroll
  for (int nt = 0; nt < 8; ++nt) acc[nt] = (f32x4){0.f, 0.f, 0.f, 0.f};
#pragma unroll
  for (int nt = 0; nt < 8; ++nt) {
#pragma unroll
    for (int kk = 0; kk < 4; ++kk) {
      short8 xb = ldsf(XS, adr_q(nt * 16 + l16, kk * 32 + g4 * 8));
      MFMA16(acc[nt], wf[kk], xb);   // D[o][n']: col=l16 -> n', row=g4*4+r -> o
    }
  }
  // two 64-row halves through the 16K WS
#pragma unroll
  for (int hf = 0; hf < 2; ++hf) {
    __syncthreads();   // WS free (previous readback complete)
#pragma unroll
    for (int nt4 = 0; nt4 < 4; ++nt4) {
      int nt = hf * 4 + nt4;
      float y0 = fmaxf(acc[nt][0] + bv4[0], 0.f);
      float y1 = fmaxf(acc[nt][1] + bv4[1], 0.f);
      float y2 = fmaxf(acc[nt][2] + bv4[2], 0.f);
      float y3 = fmaxf(acc[nt][3] + bv4[3], 0.f);
      uint2 u;
      u.x = (unsigned)f2b(y0) | ((unsigned)f2b(y1) << 16);
      u.y = (unsigned)f2b(y2) | ((unsigned)f2b(y3) << 16);
      int row = nt4 * 16 + l16;                       // 0..63
      unsigned cb = (unsigned)(wvid * 32 + g4 * 8);
      *(uint2*)(WS + (unsigned)(row << 8) + (cb ^ ((unsigned)(row & 7) << 4))) = u;
    }
    __syncthreads();
    // readback: full 256B rows, coalesced global stores
#pragma unroll
    for (int it = 0; it < 8; ++it) {
      int row = it * 8 + wvid;                        // 0..63
      unsigned u = *(const unsigned*)(WS + (unsigned)(row << 8) +
                                     (((unsigned)(l << 2)) ^ ((unsigned)(row & 7) << 4)));
      ((unsigned*)dst)[(size_t)(brel * 16384 + n0 + hf * 64 + row) * 64 + l] = u;
    }
  }
}

__global__ __launch_bounds__(512, 6) void k1_qkv(
    const float* __restrict__ rep, const unsigned short* __restrict__ wb,
    const float* __restrict__ bq, const float* __restrict__ bk,
    const float* __restrict__ bv,
    unsigned short* __restrict__ qo, unsigned short* __restrict__ ko,
    unsigned short* __restrict__ vo, int b0)
{
  extern __shared__ char smem[];
  char* XS = smem;               // 32K
  char* WS = smem + (32 << 10);  // 16K

  const int t = threadIdx.x;
  const int wvid = t >> 6, l = t & 63, l16 = l & 15, g4 = l >> 4;
  const int brel = blockIdx.x >> 7;
  const int n0 = (blockIdx.x & 127) * 128;
  const int b = b0 + brel;

#pragma unroll
  for (int it = 0; it < 8; ++it) {
    int i = it * 512 + t;
    int c = i >> 5, j4 = i & 31;
    float4 xv = *(const float4*)(rep + (size_t)(b * 128 + c) * 16384 + n0 + j4 * 4);
    float vv[4] = {xv.x, xv.y, xv.z, xv.w};
#pragma unroll
    for (int r = 0; r < 4; ++r)
      *(unsigned short*)(XS + adr_q(j4 * 4 + r, c)) = f2b(vv[r]);
  }
  __syncthreads();

  k1_one(wb,         bq, qo, XS, WS, brel, n0, wvid, l, l16, g4);
  k1_one(wb + 16384, bk, ko, XS, WS, brel, n0, wvid, l, l16, g4);
  k1_one(wb + 32768, bv, vo, XS, WS, brel, n0, wvid, l, l16, g4);
}

// ================= K2: attention per (b,w) — R5-verified, unchanged =========
// LDS: KS [256g][128c] @0 (64K), VTS [128c][256g] @64K (64K),
//      PS quarter-slices @128K (16 waves x 2K = 32K). Total 160K.

__global__ __launch_bounds__(1024, 1) void k2_attn(
    const unsigned short* __restrict__ qws, const unsigned short* __restrict__ kws,
    const unsigned short* __restrict__ vws, unsigned short* __restrict__ aws)
{
  extern __shared__ char smem[];
  char* KS  = smem;
  char* VTS = smem + (64 << 10);

  const int t = threadIdx.x;
  const int wvid = t >> 6, l = t & 63, l16 = l & 15, g4 = l >> 4;
  char* PS = smem + (128 << 10) + (wvid << 11);

  const int brel = blockIdx.x >> 6;
  const int w = blockIdx.x & 63;
  const size_t base = (size_t)brel * 16384;

#pragma unroll
  for (int it = 0; it < 4; ++it) {
    int i = it * 1024 + t;
    int g = i >> 4, c16 = i & 15;
    short8 kv = *(const short8*)(kws + (base + g * 64 + w) * 128 + c16 * 8);
    *(short8*)(KS + adr_s(g, c16 * 8)) = kv;
  }
#pragma unroll
  for (int it = 0; it < 4; ++it) {
    int i = it * 1024 + t;
    int g = i >> 4, c16 = i & 15;
    short8 vv = *(const short8*)(vws + (base + g * 64 + w) * 128 + c16 * 8);
#pragma unroll
    for (int j = 0; j < 8; ++j)
      *(unsigned short*)(VTS + adr_vt(c16 * 8 + j, g)) = (unsigned short)vv[j];
  }
  __syncthreads();

  const float SCL2 = 0.08838834764831845f * 1.4426950408889634f; // rsqrt(128)*log2e
  const int hb = wvid * 16;

  short8 qa[4];
#pragma unroll
  for (int kk = 0; kk < 4; ++kk)
    qa[kk] = *(const short8*)(qws + (base + (hb + l16) * 64 + w) * 128 + kk * 32 + g4 * 8);

  f32x4 sc[16];
#pragma unroll
  for (int gt = 0; gt < 16; ++gt) {
    f32x4 acc = {0.f, 0.f, 0.f, 0.f};
#pragma unroll
    for (int kk = 0; kk < 4; ++kk) {
      short8 kb = ldsf(KS, adr_s(gt * 16 + l16, kk * 32 + g4 * 8));
      MFMA16(acc, qa[kk], kb);
    }
    sc[gt] = acc;
  }
  float mx[4], rcps[4];
#pragma unroll
  for (int r = 0; r < 4; ++r) {
    float mm = sc[0][r];
#pragma unroll
    for (int gt = 1; gt < 16; ++gt) mm = fmaxf(mm, sc[gt][r]);
    mm = fmaxf(mm, __shfl_xor(mm, 1, 64));
    mm = fmaxf(mm, __shfl_xor(mm, 2, 64));
    mm = fmaxf(mm, __shfl_xor(mm, 4, 64));
    mm = fmaxf(mm, __shfl_xor(mm, 8, 64));
    mx[r] = mm;
  }
#pragma unroll
  for (int gt = 0; gt < 16; ++gt)
#pragma unroll
    for (int r = 0; r < 4; ++r)
      sc[gt][r] = exp2f((sc[gt][r] - mx[r]) * SCL2);
#pragma unroll
  for (int r = 0; r < 4; ++r) {
    float s = 0.f;
#pragma unroll
    for (int gt = 0; gt < 16; ++gt) s += sc[gt][r];
    s += __shfl_xor(s, 1, 64);
    s += __shfl_xor(s, 2, 64);
    s += __shfl_xor(s, 4, 64);
    s += __shfl_xor(s, 8, 64);
    rcps[r] = 1.0f / s;
  }

  f32x4 oacc[8];
#pragma unroll
  for (int nt = 0; nt < 8; ++nt) oacc[nt] = (f32x4){0.f, 0.f, 0.f, 0.f};
#pragma unroll
  for (int gh = 0; gh < 4; ++gh) {
#pragma unroll
    for (int gt4 = 0; gt4 < 4; ++gt4) {
      int gt = gh * 4 + gt4;
      int gc = gt4 * 16 + l16;
#pragma unroll
      for (int r = 0; r < 4; ++r)
        *(unsigned short*)(PS + ps_adr(g4 * 4 + r, gc)) = f2b(sc[gt][r]);
    }
#pragma unroll
    for (int kk2 = 0; kk2 < 2; ++kk2) {
      short8 pa = ldsf(PS, ps_adr(l16, kk2 * 32 + g4 * 8));
#pragma unroll
      for (int nt = 0; nt < 8; ++nt) {
        short8 vb = ldsf(VTS, adr_vt(nt * 16 + l16, gh * 64 + kk2 * 32 + g4 * 8));
        MFMA16(oacc[nt], pa, vb);
      }
    }
  }
#pragma unroll
  for (int nt = 0; nt < 8; ++nt) {
#pragma unroll
    for (int r = 0; r < 4; ++r) {
      size_t idx = (base + (size_t)(hb + g4 * 4 + r) * 64 + w) * 128 + nt * 16 + l16;
      aws[idx] = f2b(oacc[nt][r] * rcps[r]);
    }
  }
}

// ================= K3: out = relu(wfc . att^T + bfc) =====================
// grid = nbc*64; block tile = 256 n.  LDS: AS [256n][128c] (64K).

__global__ __launch_bounds__(512, 4) void k3_conv(
    const unsigned short* __restrict__ aws, const unsigned short* __restrict__ wb,
    const float* __restrict__ bfc, float* __restrict__ out, int b0)
{
  extern __shared__ char smem[];
  char* AS = smem;

  const int t = threadIdx.x;
  const int wvid = t >> 6, l = t & 63, l16 = l & 15, g4 = l >> 4;
  (void)l;
  const int brel = blockIdx.x >> 6;
  const int n0 = (blockIdx.x & 63) * 256;
  const int b = b0 + brel;

#pragma unroll
  for (int it = 0; it < 8; ++it) {
    int i = it * 512 + t;
    int n = i >> 4, c16 = i & 15;
    short8 av = *(const short8*)(aws + ((size_t)brel * 16384 + n0 + n) * 128 + c16 * 8);
    *(short8*)(AS + adr_s(n, c16 * 8)) = av;
  }
  __syncthreads();

  const int strip = wvid * 16;
  const unsigned short* wfcb = wb + 3 * 16384;
  short8 wf[4];
#pragma unroll
  for (int kk = 0; kk < 4; ++kk)
    wf[kk] = *(const short8*)(wfcb + (strip + l16) * 128 + kk * 32 + g4 * 8);
  float bv4[4];
#pragma unroll
  for (int r = 0; r < 4; ++r) bv4[r] = bfc[strip + g4 * 4 + r];

#pragma unroll
  for (int nt = 0; nt < 16; ++nt) {
    f32x4 acc = {0.f, 0.f, 0.f, 0.f};
#pragma unroll
    for (int kk = 0; kk < 4; ++kk) {
      short8 ab = ldsf(AS, adr_s(nt * 16 + l16, kk * 32 + g4 * 8));
      MFMA16(acc, wf[kk], ab);
    }
#pragma unroll
    for (int r = 0; r < 4; ++r) {
      int o = strip + g4 * 4 + r;
      out[(size_t)(b * 128 + o) * 16384 + n0 + nt * 16 + l16] = fmaxf(acc[r] + bv4[r], 0.f);
    }
  }
}

extern "C" void kernel_launch(void* const* d_in, const int* in_sizes, int n_in,
                              void* d_out, int out_size, void* d_ws, size_t ws_size,
                              hipStream_t stream) {
  const float* rep = (const float*)d_in[0];
  const float* wq  = (const float*)d_in[1];
  const float* bq  = (const float*)d_in[2];
  const float* wk  = (const float*)d_in[3];
  const float* bk  = (const float*)d_in[4];
  const float* wv  = (const float*)d_in[5];
  const float* bv  = (const float*)d_in[6];
  const float* wfc = (const float*)d_in[7];
  const float* bfc = (const float*)d_in[8];
  float* out = (float*)d_out;
  (void)in_sizes; (void)n_in; (void)out_size;

  hipFuncSetAttribute((const void*)k1_qkv,  hipFuncAttributeMaxDynamicSharedMemorySize, 48 * 1024);
  hipFuncSetAttribute((const void*)k2_attn, hipFuncAttributeMaxDynamicSharedMemorySize, 160 * 1024);
  hipFuncSetAttribute((const void*)k3_conv, hipFuncAttributeMaxDynamicSharedMemorySize, 64 * 1024);

  const size_t wb_bytes = 4 * 16384 * 2;          // 128 KB bf16 weights
  const size_t per_b = (size_t)16384 * 128 * 2;   // 4 MiB per array per b
  if (ws_size < wb_bytes + 4 * per_b) return;     // needs >= ~16.1 MB
  size_t nb_max = (ws_size - wb_bytes) / (4 * per_b);
  int nb = (int)(nb_max < 16 ? nb_max : 16);

  char* ws = (char*)d_ws;
  unsigned short* qws = (unsigned short*)(ws);
  unsigned short* kws = (unsigned short*)(ws + (size_t)nb * per_b);
  unsigned short* vws = (unsigned short*)(ws + (size_t)nb * per_b * 2);
  unsigned short* aws = (unsigned short*)(ws + (size_t)nb * per_b * 3);
  unsigned short* wb  = (unsigned short*)(ws + (size_t)nb * per_b * 4);

  k0_wcvt<<<dim3(64), dim3(256), 0, stream>>>(wq, wk, wv, wfc, wb);

  for (int b0 = 0; b0 < 16; b0 += nb) {
    int nbc = (16 - b0) < nb ? (16 - b0) : nb;
    k1_qkv<<<dim3(nbc * 128), dim3(512), 48 * 1024, stream>>>(
        rep, wb, bq, bk, bv, qws, kws, vws, b0);
    k2_attn<<<dim3(nbc * 64), dim3(1024), 160 * 1024, stream>>>(qws, kws, vws, aws);
    k3_conv<<<dim3(nbc * 64), dim3(512), 64 * 1024, stream>>>(aws, wb, bfc, out, b0);
  }
}

// Round 7
// 251.668 us; speedup vs baseline: 1.3176x; 1.3176x over previous
//
#include <hip/hip_runtime.h>

// B=16, C=128, H=256, W=64.  Pipeline:
//  K0: convert wq/wk/wv/wfc fp32->bf16 into ws tail (once per launch)
//  K1: Q/K/V = relu(Wx+b) -> ws [b][n=h*64+w][c] bf16; 16KB half-staged
//      row writes, 48KB LDS -> 3 blocks/CU.  LB(512,4): LB(512,6) forced
//      VGPR=40 -> scratch spills (+450MB HBM traffic, R6 regression).
//  K2: per-(b,w) attention over H (R5-verified, untouched)
//  K3: out = relu(wfc . att^T + bfc), bf16 weights

typedef __attribute__((ext_vector_type(8))) short short8;
typedef __attribute__((ext_vector_type(4))) float f32x4;

#define MFMA16(acc, a, b) (acc) = __builtin_amdgcn_mfma_f32_16x16x32_bf16((a), (b), (acc), 0, 0, 0)

__device__ __forceinline__ unsigned short f2b(float f) {
  unsigned u = __builtin_bit_cast(unsigned, f);
  u = (u + 0x7fffu + ((u >> 16) & 1u)) >> 16;   // RNE
  return (unsigned short)u;
}

// [R][128c] bf16 tile, row-XOR swizzle (verified write-scalar/read-b128 pair)
__device__ __forceinline__ unsigned adr_s(int r, int c) {
  return (unsigned)(((r << 8) + (c << 1)) ^ ((r & 7) << 4));
}
// K1's XS [128j][128c]: stronger row-hash (rows written in stride-4 bursts)
__device__ __forceinline__ unsigned adr_q(int r, int c) {
  return (unsigned)(((r << 8) + (c << 1)) ^ (((r ^ (r >> 3)) & 7) << 4));
}
// V^T tile [128c][256g] (R5-verified double-XOR)
__device__ __forceinline__ unsigned adr_vt(int c, int g) {
  unsigned blk = (unsigned)(((g >> 3) ^ (c & 7) ^ ((c >> 3) & 7)) & 31);
  return (unsigned)((c << 9) + (blk << 4) + ((g & 7) << 1));
}
// per-wave P quarter-slice [16r][64c] bf16 (2KB), row-hash (R5-verified)
__device__ __forceinline__ unsigned ps_adr(int r, int c) {
  return (unsigned)(((r << 7) + (c << 1)) ^ (((r ^ (r >> 3)) & 7) << 4));
}

__device__ __forceinline__ short8 ldsf(const char* p, unsigned off) {
  return *(const short8*)(p + off);
}

// ================= K0: weight pre-convert fp32 -> bf16 =================
// wb layout: [4 matrices][128 o][128 c] bf16, same row-major as source.
__global__ __launch_bounds__(256) void k0_wcvt(
    const float* __restrict__ wq, const float* __restrict__ wk,
    const float* __restrict__ wv, const float* __restrict__ wfc,
    unsigned short* __restrict__ wb)
{
  int i = blockIdx.x * 256 + threadIdx.x;    // 16384 float4's total
  int mat = i >> 12, off = (i & 4095) * 4;
  const float* src = (mat == 0) ? wq : (mat == 1) ? wk : (mat == 2) ? wv : wfc;
  float4 v = *(const float4*)(src + off);
  uint2 u;
  u.x = (unsigned)f2b(v.x) | ((unsigned)f2b(v.y) << 16);
  u.y = (unsigned)f2b(v.z) | ((unsigned)f2b(v.w) << 16);
  *(uint2*)(wb + mat * 16384 + off) = u;
}

// ================= K1: QKV projection =================
// grid = nbc*128; block tile = 128 n.
// LDS: XS [128n][128c] @0 (32K), WS half-stage [64n][128c] @32K (16K). 48K total.

__device__ __forceinline__ void k1_one(const unsigned short* wmat, const float* bias,
    unsigned short* dst, const char* XS, char* WS,
    int brel, int n0, int wvid, int l, int l16, int g4) {
  const int strip = wvid * 16;
  short8 wf[4];
#pragma unroll
  for (int kk = 0; kk < 4; ++kk)
    wf[kk] = *(const short8*)(wmat + (strip + l16) * 128 + kk * 32 + g4 * 8);
  float bv4[4];
#pragma unroll
  for (int r = 0; r < 4; ++r) bv4[r] = bias[strip + g4 * 4 + r];

  f32x4 acc[8];
#pragma unroll
  for (int nt = 0; nt < 8; ++nt) acc[nt] = (f32x4){0.f, 0.f, 0.f, 0.f};
#pragma unroll
  for (int nt = 0; nt < 8; ++nt) {
#pragma unroll
    for (int kk = 0; kk < 4; ++kk) {
      short8 xb = ldsf(XS, adr_q(nt * 16 + l16, kk * 32 + g4 * 8));
      MFMA16(acc[nt], wf[kk], xb);   // D[o][n']: col=l16 -> n', row=g4*4+r -> o
    }
  }
  // two 64-row halves through the 16K WS
#pragma unroll
  for (int hf = 0; hf < 2; ++hf) {
    __syncthreads();   // WS free (previous readback complete)
#pragma unroll
    for (int nt4 = 0; nt4 < 4; ++nt4) {
      int nt = hf * 4 + nt4;
      float y0 = fmaxf(acc[nt][0] + bv4[0], 0.f);
      float y1 = fmaxf(acc[nt][1] + bv4[1], 0.f);
      float y2 = fmaxf(acc[nt][2] + bv4[2], 0.f);
      float y3 = fmaxf(acc[nt][3] + bv4[3], 0.f);
      uint2 u;
      u.x = (unsigned)f2b(y0) | ((unsigned)f2b(y1) << 16);
      u.y = (unsigned)f2b(y2) | ((unsigned)f2b(y3) << 16);
      int row = nt4 * 16 + l16;                       // 0..63
      unsigned cb = (unsigned)(wvid * 32 + g4 * 8);
      *(uint2*)(WS + (unsigned)(row << 8) + (cb ^ ((unsigned)(row & 7) << 4))) = u;
    }
    __syncthreads();
    // readback: full 256B rows, coalesced global stores
#pragma unroll
    for (int it = 0; it < 8; ++it) {
      int row = it * 8 + wvid;                        // 0..63
      unsigned u = *(const unsigned*)(WS + (unsigned)(row << 8) +
                                     (((unsigned)(l << 2)) ^ ((unsigned)(row & 7) << 4)));
      ((unsigned*)dst)[(size_t)(brel * 16384 + n0 + hf * 64 + row) * 64 + l] = u;
    }
  }
}

__global__ __launch_bounds__(512, 4) void k1_qkv(
    const float* __restrict__ rep, const unsigned short* __restrict__ wb,
    const float* __restrict__ bq, const float* __restrict__ bk,
    const float* __restrict__ bv,
    unsigned short* __restrict__ qo, unsigned short* __restrict__ ko,
    unsigned short* __restrict__ vo, int b0)
{
  extern __shared__ char smem[];
  char* XS = smem;               // 32K
  char* WS = smem + (32 << 10);  // 16K

  const int t = threadIdx.x;
  const int wvid = t >> 6, l = t & 63, l16 = l & 15, g4 = l >> 4;
  const int brel = blockIdx.x >> 7;
  const int n0 = (blockIdx.x & 127) * 128;
  const int b = b0 + brel;

#pragma unroll
  for (int it = 0; it < 8; ++it) {
    int i = it * 512 + t;
    int c = i >> 5, j4 = i & 31;
    float4 xv = *(const float4*)(rep + (size_t)(b * 128 + c) * 16384 + n0 + j4 * 4);
    float vv[4] = {xv.x, xv.y, xv.z, xv.w};
#pragma unroll
    for (int r = 0; r < 4; ++r)
      *(unsigned short*)(XS + adr_q(j4 * 4 + r, c)) = f2b(vv[r]);
  }
  __syncthreads();

  k1_one(wb,         bq, qo, XS, WS, brel, n0, wvid, l, l16, g4);
  k1_one(wb + 16384, bk, ko, XS, WS, brel, n0, wvid, l, l16, g4);
  k1_one(wb + 32768, bv, vo, XS, WS, brel, n0, wvid, l, l16, g4);
}

// ================= K2: attention per (b,w) — R5-verified, unchanged =========
// LDS: KS [256g][128c] @0 (64K), VTS [128c][256g] @64K (64K),
//      PS quarter-slices @128K (16 waves x 2K = 32K). Total 160K.

__global__ __launch_bounds__(1024, 1) void k2_attn(
    const unsigned short* __restrict__ qws, const unsigned short* __restrict__ kws,
    const unsigned short* __restrict__ vws, unsigned short* __restrict__ aws)
{
  extern __shared__ char smem[];
  char* KS  = smem;
  char* VTS = smem + (64 << 10);

  const int t = threadIdx.x;
  const int wvid = t >> 6, l = t & 63, l16 = l & 15, g4 = l >> 4;
  char* PS = smem + (128 << 10) + (wvid << 11);

  const int brel = blockIdx.x >> 6;
  const int w = blockIdx.x & 63;
  const size_t base = (size_t)brel * 16384;

#pragma unroll
  for (int it = 0; it < 4; ++it) {
    int i = it * 1024 + t;
    int g = i >> 4, c16 = i & 15;
    short8 kv = *(const short8*)(kws + (base + g * 64 + w) * 128 + c16 * 8);
    *(short8*)(KS + adr_s(g, c16 * 8)) = kv;
  }
#pragma unroll
  for (int it = 0; it < 4; ++it) {
    int i = it * 1024 + t;
    int g = i >> 4, c16 = i & 15;
    short8 vv = *(const short8*)(vws + (base + g * 64 + w) * 128 + c16 * 8);
#pragma unroll
    for (int j = 0; j < 8; ++j)
      *(unsigned short*)(VTS + adr_vt(c16 * 8 + j, g)) = (unsigned short)vv[j];
  }
  __syncthreads();

  const float SCL2 = 0.08838834764831845f * 1.4426950408889634f; // rsqrt(128)*log2e
  const int hb = wvid * 16;

  short8 qa[4];
#pragma unroll
  for (int kk = 0; kk < 4; ++kk)
    qa[kk] = *(const short8*)(qws + (base + (hb + l16) * 64 + w) * 128 + kk * 32 + g4 * 8);

  f32x4 sc[16];
#pragma unroll
  for (int gt = 0; gt < 16; ++gt) {
    f32x4 acc = {0.f, 0.f, 0.f, 0.f};
#pragma unroll
    for (int kk = 0; kk < 4; ++kk) {
      short8 kb = ldsf(KS, adr_s(gt * 16 + l16, kk * 32 + g4 * 8));
      MFMA16(acc, qa[kk], kb);
    }
    sc[gt] = acc;
  }
  float mx[4], rcps[4];
#pragma unroll
  for (int r = 0; r < 4; ++r) {
    float mm = sc[0][r];
#pragma unroll
    for (int gt = 1; gt < 16; ++gt) mm = fmaxf(mm, sc[gt][r]);
    mm = fmaxf(mm, __shfl_xor(mm, 1, 64));
    mm = fmaxf(mm, __shfl_xor(mm, 2, 64));
    mm = fmaxf(mm, __shfl_xor(mm, 4, 64));
    mm = fmaxf(mm, __shfl_xor(mm, 8, 64));
    mx[r] = mm;
  }
#pragma unroll
  for (int gt = 0; gt < 16; ++gt)
#pragma unroll
    for (int r = 0; r < 4; ++r)
      sc[gt][r] = exp2f((sc[gt][r] - mx[r]) * SCL2);
#pragma unroll
  for (int r = 0; r < 4; ++r) {
    float s = 0.f;
#pragma unroll
    for (int gt = 0; gt < 16; ++gt) s += sc[gt][r];
    s += __shfl_xor(s, 1, 64);
    s += __shfl_xor(s, 2, 64);
    s += __shfl_xor(s, 4, 64);
    s += __shfl_xor(s, 8, 64);
    rcps[r] = 1.0f / s;
  }

  f32x4 oacc[8];
#pragma unroll
  for (int nt = 0; nt < 8; ++nt) oacc[nt] = (f32x4){0.f, 0.f, 0.f, 0.f};
#pragma unroll
  for (int gh = 0; gh < 4; ++gh) {
#pragma unroll
    for (int gt4 = 0; gt4 < 4; ++gt4) {
      int gt = gh * 4 + gt4;
      int gc = gt4 * 16 + l16;
#pragma unroll
      for (int r = 0; r < 4; ++r)
        *(unsigned short*)(PS + ps_adr(g4 * 4 + r, gc)) = f2b(sc[gt][r]);
    }
#pragma unroll
    for (int kk2 = 0; kk2 < 2; ++kk2) {
      short8 pa = ldsf(PS, ps_adr(l16, kk2 * 32 + g4 * 8));
#pragma unroll
      for (int nt = 0; nt < 8; ++nt) {
        short8 vb = ldsf(VTS, adr_vt(nt * 16 + l16, gh * 64 + kk2 * 32 + g4 * 8));
        MFMA16(oacc[nt], pa, vb);
      }
    }
  }
#pragma unroll
  for (int nt = 0; nt < 8; ++nt) {
#pragma unroll
    for (int r = 0; r < 4; ++r) {
      size_t idx = (base + (size_t)(hb + g4 * 4 + r) * 64 + w) * 128 + nt * 16 + l16;
      aws[idx] = f2b(oacc[nt][r] * rcps[r]);
    }
  }
}

// ================= K3: out = relu(wfc . att^T + bfc) =====================
// grid = nbc*64; block tile = 256 n.  LDS: AS [256n][128c] (64K).

__global__ __launch_bounds__(512, 4) void k3_conv(
    const unsigned short* __restrict__ aws, const unsigned short* __restrict__ wb,
    const float* __restrict__ bfc, float* __restrict__ out, int b0)
{
  extern __shared__ char smem[];
  char* AS = smem;

  const int t = threadIdx.x;
  const int wvid = t >> 6, l = t & 63, l16 = l & 15, g4 = l >> 4;
  (void)l;
  const int brel = blockIdx.x >> 6;
  const int n0 = (blockIdx.x & 63) * 256;
  const int b = b0 + brel;

#pragma unroll
  for (int it = 0; it < 8; ++it) {
    int i = it * 512 + t;
    int n = i >> 4, c16 = i & 15;
    short8 av = *(const short8*)(aws + ((size_t)brel * 16384 + n0 + n) * 128 + c16 * 8);
    *(short8*)(AS + adr_s(n, c16 * 8)) = av;
  }
  __syncthreads();

  const int strip = wvid * 16;
  const unsigned short* wfcb = wb + 3 * 16384;
  short8 wf[4];
#pragma unroll
  for (int kk = 0; kk < 4; ++kk)
    wf[kk] = *(const short8*)(wfcb + (strip + l16) * 128 + kk * 32 + g4 * 8);
  float bv4[4];
#pragma unroll
  for (int r = 0; r < 4; ++r) bv4[r] = bfc[strip + g4 * 4 + r];

#pragma unroll
  for (int nt = 0; nt < 16; ++nt) {
    f32x4 acc = {0.f, 0.f, 0.f, 0.f};
#pragma unroll
    for (int kk = 0; kk < 4; ++kk) {
      short8 ab = ldsf(AS, adr_s(nt * 16 + l16, kk * 32 + g4 * 8));
      MFMA16(acc, wf[kk], ab);
    }
#pragma unroll
    for (int r = 0; r < 4; ++r) {
      int o = strip + g4 * 4 + r;
      out[(size_t)(b * 128 + o) * 16384 + n0 + nt * 16 + l16] = fmaxf(acc[r] + bv4[r], 0.f);
    }
  }
}

extern "C" void kernel_launch(void* const* d_in, const int* in_sizes, int n_in,
                              void* d_out, int out_size, void* d_ws, size_t ws_size,
                              hipStream_t stream) {
  const float* rep = (const float*)d_in[0];
  const float* wq  = (const float*)d_in[1];
  const float* bq  = (const float*)d_in[2];
  const float* wk  = (const float*)d_in[3];
  const float* bk  = (const float*)d_in[4];
  const float* wv  = (const float*)d_in[5];
  const float* bv  = (const float*)d_in[6];
  const float* wfc = (const float*)d_in[7];
  const float* bfc = (const float*)d_in[8];
  float* out = (float*)d_out;
  (void)in_sizes; (void)n_in; (void)out_size;

  hipFuncSetAttribute((const void*)k1_qkv,  hipFuncAttributeMaxDynamicSharedMemorySize, 48 * 1024);
  hipFuncSetAttribute((const void*)k2_attn, hipFuncAttributeMaxDynamicSharedMemorySize, 160 * 1024);
  hipFuncSetAttribute((const void*)k3_conv, hipFuncAttributeMaxDynamicSharedMemorySize, 64 * 1024);

  const size_t wb_bytes = 4 * 16384 * 2;          // 128 KB bf16 weights
  const size_t per_b = (size_t)16384 * 128 * 2;   // 4 MiB per array per b
  if (ws_size < wb_bytes + 4 * per_b) return;     // needs >= ~16.1 MB
  size_t nb_max = (ws_size - wb_bytes) / (4 * per_b);
  int nb = (int)(nb_max < 16 ? nb_max : 16);

  char* ws = (char*)d_ws;
  unsigned short* qws = (unsigned short*)(ws);
  unsigned short* kws = (unsigned short*)(ws + (size_t)nb * per_b);
  unsigned short* vws = (unsigned short*)(ws + (size_t)nb * per_b * 2);
  unsigned short* aws = (unsigned short*)(ws + (size_t)nb * per_b * 3);
  unsigned short* wb  = (unsigned short*)(ws + (size_t)nb * per_b * 4);

  k0_wcvt<<<dim3(64), dim3(256), 0, stream>>>(wq, wk, wv, wfc, wb);

  for (int b0 = 0; b0 < 16; b0 += nb) {
    int nbc = (16 - b0) < nb ? (16 - b0) : nb;
    k1_qkv<<<dim3(nbc * 128), dim3(512), 48 * 1024, stream>>>(
        rep, wb, bq, bk, bv, qws, kws, vws, b0);
    k2_attn<<<dim3(nbc * 64), dim3(1024), 160 * 1024, stream>>>(qws, kws, vws, aws);
    k3_conv<<<dim3(nbc * 64), dim3(512), 64 * 1024, stream>>>(aws, wb, bfc, out, b0);
  }
}

// Round 8
// 249.397 us; speedup vs baseline: 1.3296x; 1.0091x over previous
//
#include <hip/hip_runtime.h>

// B=16, C=128, H=256, W=64.  Pipeline (workspace now W-MAJOR: [b][w][h][c]):
//  K0: convert wq/wk/wv/wfc fp32->bf16 into ws tail
//  K1: Q/K/V = relu(Wx+b) -> ws [b][w][h][c] bf16; 16KB half-staged row writes
//  K2: per-(b,w) attention; all global accesses now contiguous 64KB/block
//  K3: out = relu(wfc . att^T + bfc) -> [b][o][n] fp32 coalesced

typedef __attribute__((ext_vector_type(8))) short short8;
typedef __attribute__((ext_vector_type(4))) float f32x4;

#define MFMA16(acc, a, b) (acc) = __builtin_amdgcn_mfma_f32_16x16x32_bf16((a), (b), (acc), 0, 0, 0)

__device__ __forceinline__ unsigned short f2b(float f) {
  unsigned u = __builtin_bit_cast(unsigned, f);
  u = (u + 0x7fffu + ((u >> 16) & 1u)) >> 16;   // RNE
  return (unsigned short)u;
}

// [R][128c] bf16 tile, row-XOR swizzle (verified write-scalar/read-b128 pair)
__device__ __forceinline__ unsigned adr_s(int r, int c) {
  return (unsigned)(((r << 8) + (c << 1)) ^ ((r & 7) << 4));
}
// K1's XS [128j][128c]: stronger row-hash (rows written in stride-4 bursts)
__device__ __forceinline__ unsigned adr_q(int r, int c) {
  return (unsigned)(((r << 8) + (c << 1)) ^ (((r ^ (r >> 3)) & 7) << 4));
}
// V^T tile [128c][256g] (R5-verified double-XOR)
__device__ __forceinline__ unsigned adr_vt(int c, int g) {
  unsigned blk = (unsigned)(((g >> 3) ^ (c & 7) ^ ((c >> 3) & 7)) & 31);
  return (unsigned)((c << 9) + (blk << 4) + ((g & 7) << 1));
}
// per-wave P quarter-slice [16r][64c] bf16 (2KB), row-hash (R5-verified)
__device__ __forceinline__ unsigned ps_adr(int r, int c) {
  return (unsigned)(((r << 7) + (c << 1)) ^ (((r ^ (r >> 3)) & 7) << 4));
}

__device__ __forceinline__ short8 ldsf(const char* p, unsigned off) {
  return *(const short8*)(p + off);
}

// ================= K0: weight pre-convert fp32 -> bf16 =================
__global__ __launch_bounds__(256) void k0_wcvt(
    const float* __restrict__ wq, const float* __restrict__ wk,
    const float* __restrict__ wv, const float* __restrict__ wfc,
    unsigned short* __restrict__ wb)
{
  int i = blockIdx.x * 256 + threadIdx.x;    // 16384 float4's total
  int mat = i >> 12, off = (i & 4095) * 4;
  const float* src = (mat == 0) ? wq : (mat == 1) ? wk : (mat == 2) ? wv : wfc;
  float4 v = *(const float4*)(src + off);
  uint2 u;
  u.x = (unsigned)f2b(v.x) | ((unsigned)f2b(v.y) << 16);
  u.y = (unsigned)f2b(v.z) | ((unsigned)f2b(v.w) << 16);
  *(uint2*)(wb + mat * 16384 + off) = u;
}

// ================= K1: QKV projection =================
// grid = nbc*128; block tile = 128 n (n = h*64+w).
// LDS: XS [128n][128c] @0 (32K), WS half-stage [64n][128c] @32K (16K). 48K.
// Output W-MAJOR: dst[((brel*64+w)*256 + h)*128 + c].

__device__ __forceinline__ void k1_one(const unsigned short* wmat, const float* bias,
    unsigned short* dst, const char* XS, char* WS,
    int brel, int n0, int wvid, int l, int l16, int g4) {
  const int strip = wvid * 16;
  short8 wf[4];
#pragma unroll
  for (int kk = 0; kk < 4; ++kk)
    wf[kk] = *(const short8*)(wmat + (strip + l16) * 128 + kk * 32 + g4 * 8);
  float bv4[4];
#pragma unroll
  for (int r = 0; r < 4; ++r) bv4[r] = bias[strip + g4 * 4 + r];

  f32x4 acc[8];
#pragma unroll
  for (int nt = 0; nt < 8; ++nt) acc[nt] = (f32x4){0.f, 0.f, 0.f, 0.f};
#pragma unroll
  for (int nt = 0; nt < 8; ++nt) {
#pragma unroll
    for (int kk = 0; kk < 4; ++kk) {
      short8 xb = ldsf(XS, adr_q(nt * 16 + l16, kk * 32 + g4 * 8));
      MFMA16(acc[nt], wf[kk], xb);   // D[o][n']: col=l16 -> n', row=g4*4+r -> o
    }
  }
  // two 64-row halves through the 16K WS
#pragma unroll
  for (int hf = 0; hf < 2; ++hf) {
    __syncthreads();   // WS free (previous readback complete)
#pragma unroll
    for (int nt4 = 0; nt4 < 4; ++nt4) {
      int nt = hf * 4 + nt4;
      float y0 = fmaxf(acc[nt][0] + bv4[0], 0.f);
      float y1 = fmaxf(acc[nt][1] + bv4[1], 0.f);
      float y2 = fmaxf(acc[nt][2] + bv4[2], 0.f);
      float y3 = fmaxf(acc[nt][3] + bv4[3], 0.f);
      uint2 u;
      u.x = (unsigned)f2b(y0) | ((unsigned)f2b(y1) << 16);
      u.y = (unsigned)f2b(y2) | ((unsigned)f2b(y3) << 16);
      int row = nt4 * 16 + l16;                       // 0..63
      unsigned cb = (unsigned)(wvid * 32 + g4 * 8);
      *(uint2*)(WS + (unsigned)(row << 8) + (cb ^ ((unsigned)(row & 7) << 4))) = u;
    }
    __syncthreads();
    // readback full 256B rows -> w-major global rows
#pragma unroll
    for (int it = 0; it < 8; ++it) {
      int row = it * 8 + wvid;                        // 0..63
      unsigned u = *(const unsigned*)(WS + (unsigned)(row << 8) +
                                     (((unsigned)(l << 2)) ^ ((unsigned)(row & 7) << 4)));
      int n = n0 + hf * 64 + row;
      int h = n >> 6, w = n & 63;
      ((unsigned*)dst)[(size_t)((brel * 64 + w) * 256 + h) * 64 + l] = u;
    }
  }
}

__global__ __launch_bounds__(512, 4) void k1_qkv(
    const float* __restrict__ rep, const unsigned short* __restrict__ wb,
    const float* __restrict__ bq, const float* __restrict__ bk,
    const float* __restrict__ bv,
    unsigned short* __restrict__ qo, unsigned short* __restrict__ ko,
    unsigned short* __restrict__ vo, int b0)
{
  extern __shared__ char smem[];
  char* XS = smem;               // 32K
  char* WS = smem + (32 << 10);  // 16K

  const int t = threadIdx.x;
  const int wvid = t >> 6, l = t & 63, l16 = l & 15, g4 = l >> 4;
  const int brel = blockIdx.x >> 7;
  const int n0 = (blockIdx.x & 127) * 128;
  const int b = b0 + brel;

#pragma unroll
  for (int it = 0; it < 8; ++it) {
    int i = it * 512 + t;
    int c = i >> 5, j4 = i & 31;
    float4 xv = *(const float4*)(rep + (size_t)(b * 128 + c) * 16384 + n0 + j4 * 4);
    float vv[4] = {xv.x, xv.y, xv.z, xv.w};
#pragma unroll
    for (int r = 0; r < 4; ++r)
      *(unsigned short*)(XS + adr_q(j4 * 4 + r, c)) = f2b(vv[r]);
  }
  __syncthreads();

  k1_one(wb,         bq, qo, XS, WS, brel, n0, wvid, l, l16, g4);
  k1_one(wb + 16384, bk, ko, XS, WS, brel, n0, wvid, l, l16, g4);
  k1_one(wb + 32768, bv, vo, XS, WS, brel, n0, wvid, l, l16, g4);
}

// ================= K2: attention per (b,w) =================
// All ws accesses contiguous (w-major). LDS: KS 64K @0, VTS 64K @64K,
// PS 16x2K @128K. Total 160K.

__global__ __launch_bounds__(1024, 1) void k2_attn(
    const unsigned short* __restrict__ qws, const unsigned short* __restrict__ kws,
    const unsigned short* __restrict__ vws, unsigned short* __restrict__ aws)
{
  extern __shared__ char smem[];
  char* KS  = smem;
  char* VTS = smem + (64 << 10);

  const int t = threadIdx.x;
  const int wvid = t >> 6, l = t & 63, l16 = l & 15, g4 = l >> 4;
  char* PS = smem + (128 << 10) + (wvid << 11);

  const int brel = blockIdx.x >> 6;
  const int w = blockIdx.x & 63;
  const size_t wbase = (size_t)((brel * 64 + w)) * 256;   // row index of (b,w,h=0)

  const int hb = wvid * 16;

  // q loads first (contiguous 4KB/wave), overlap with staging below
  short8 qa[4];
#pragma unroll
  for (int kk = 0; kk < 4; ++kk)
    qa[kk] = *(const short8*)(qws + (wbase + hb + l16) * 128 + kk * 32 + g4 * 8);

  // stage K rows [g][c] — contiguous 64KB
#pragma unroll
  for (int it = 0; it < 4; ++it) {
    int i = it * 1024 + t;
    int g = i >> 4, c16 = i & 15;
    short8 kv = *(const short8*)(kws + (wbase + g) * 128 + c16 * 8);
    *(short8*)(KS + adr_s(g, c16 * 8)) = kv;
  }
  // stage V^T [c][g] — contiguous reads, scalar swizzled writes
#pragma unroll
  for (int it = 0; it < 4; ++it) {
    int i = it * 1024 + t;
    int g = i >> 4, c16 = i & 15;
    short8 vv = *(const short8*)(vws + (wbase + g) * 128 + c16 * 8);
#pragma unroll
    for (int j = 0; j < 8; ++j)
      *(unsigned short*)(VTS + adr_vt(c16 * 8 + j, g)) = (unsigned short)vv[j];
  }
  __syncthreads();

  const float SCL2 = 0.08838834764831845f * 1.4426950408889634f; // rsqrt(128)*log2e

  f32x4 sc[16];
#pragma unroll
  for (int gt = 0; gt < 16; ++gt) {
    f32x4 acc = {0.f, 0.f, 0.f, 0.f};
#pragma unroll
    for (int kk = 0; kk < 4; ++kk) {
      short8 kb = ldsf(KS, adr_s(gt * 16 + l16, kk * 32 + g4 * 8));
      MFMA16(acc, qa[kk], kb);
    }
    sc[gt] = acc;
  }
  float mx[4], rcps[4];
#pragma unroll
  for (int r = 0; r < 4; ++r) {
    float mm = sc[0][r];
#pragma unroll
    for (int gt = 1; gt < 16; ++gt) mm = fmaxf(mm, sc[gt][r]);
    mm = fmaxf(mm, __shfl_xor(mm, 1, 64));
    mm = fmaxf(mm, __shfl_xor(mm, 2, 64));
    mm = fmaxf(mm, __shfl_xor(mm, 4, 64));
    mm = fmaxf(mm, __shfl_xor(mm, 8, 64));
    mx[r] = mm;
  }
#pragma unroll
  for (int gt = 0; gt < 16; ++gt)
#pragma unroll
    for (int r = 0; r < 4; ++r)
      sc[gt][r] = exp2f((sc[gt][r] - mx[r]) * SCL2);
#pragma unroll
  for (int r = 0; r < 4; ++r) {
    float s = 0.f;
#pragma unroll
    for (int gt = 0; gt < 16; ++gt) s += sc[gt][r];
    s += __shfl_xor(s, 1, 64);
    s += __shfl_xor(s, 2, 64);
    s += __shfl_xor(s, 4, 64);
    s += __shfl_xor(s, 8, 64);
    rcps[r] = 1.0f / s;
  }

  f32x4 oacc[8];
#pragma unroll
  for (int nt = 0; nt < 8; ++nt) oacc[nt] = (f32x4){0.f, 0.f, 0.f, 0.f};
#pragma unroll
  for (int gh = 0; gh < 4; ++gh) {
#pragma unroll
    for (int gt4 = 0; gt4 < 4; ++gt4) {
      int gt = gh * 4 + gt4;
      int gc = gt4 * 16 + l16;
#pragma unroll
      for (int r = 0; r < 4; ++r)
        *(unsigned short*)(PS + ps_adr(g4 * 4 + r, gc)) = f2b(sc[gt][r]);
    }
#pragma unroll
    for (int kk2 = 0; kk2 < 2; ++kk2) {
      short8 pa = ldsf(PS, ps_adr(l16, kk2 * 32 + g4 * 8));
#pragma unroll
      for (int nt = 0; nt < 8; ++nt) {
        short8 vb = ldsf(VTS, adr_vt(nt * 16 + l16, gh * 64 + kk2 * 32 + g4 * 8));
        MFMA16(oacc[nt], pa, vb);
      }
    }
  }
  // att[w-major]: row (b,w,h) contiguous 256B; block writes contiguous 64KB
#pragma unroll
  for (int nt = 0; nt < 8; ++nt) {
#pragma unroll
    for (int r = 0; r < 4; ++r) {
      size_t idx = (wbase + hb + g4 * 4 + r) * 128 + nt * 16 + l16;
      aws[idx] = f2b(oacc[nt][r] * rcps[r]);
    }
  }
}

// ================= K3: out = relu(wfc . att^T + bfc) =====================
// grid = nbc*64; block tile = 256 n.  LDS: AS [256n][128c] (64K).

__global__ __launch_bounds__(512, 4) void k3_conv(
    const unsigned short* __restrict__ aws, const unsigned short* __restrict__ wb,
    const float* __restrict__ bfc, float* __restrict__ out, int b0)
{
  extern __shared__ char smem[];
  char* AS = smem;

  const int t = threadIdx.x;
  const int wvid = t >> 6, l = t & 63, l16 = l & 15, g4 = l >> 4;
  (void)l;
  const int brel = blockIdx.x >> 6;
  const int n0 = (blockIdx.x & 63) * 256;
  const int b = b0 + brel;

#pragma unroll
  for (int it = 0; it < 8; ++it) {
    int i = it * 512 + t;
    int nn = i >> 4, c16 = i & 15;
    int n = n0 + nn;
    int h = n >> 6, w = n & 63;
    short8 av = *(const short8*)(aws + ((size_t)((brel * 64 + w) * 256 + h)) * 128 + c16 * 8);
    *(short8*)(AS + adr_s(nn, c16 * 8)) = av;
  }
  __syncthreads();

  const int strip = wvid * 16;
  const unsigned short* wfcb = wb + 3 * 16384;
  short8 wf[4];
#pragma unroll
  for (int kk = 0; kk < 4; ++kk)
    wf[kk] = *(const short8*)(wfcb + (strip + l16) * 128 + kk * 32 + g4 * 8);
  float bv4[4];
#pragma unroll
  for (int r = 0; r < 4; ++r) bv4[r] = bfc[strip + g4 * 4 + r];

#pragma unroll
  for (int nt = 0; nt < 16; ++nt) {
    f32x4 acc = {0.f, 0.f, 0.f, 0.f};
#pragma unroll
    for (int kk = 0; kk < 4; ++kk) {
      short8 ab = ldsf(AS, adr_s(nt * 16 + l16, kk * 32 + g4 * 8));
      MFMA16(acc, wf[kk], ab);
    }
#pragma unroll
    for (int r = 0; r < 4; ++r) {
      int o = strip + g4 * 4 + r;
      out[(size_t)(b * 128 + o) * 16384 + n0 + nt * 16 + l16] = fmaxf(acc[r] + bv4[r], 0.f);
    }
  }
}

extern "C" void kernel_launch(void* const* d_in, const int* in_sizes, int n_in,
                              void* d_out, int out_size, void* d_ws, size_t ws_size,
                              hipStream_t stream) {
  const float* rep = (const float*)d_in[0];
  const float* wq  = (const float*)d_in[1];
  const float* bq  = (const float*)d_in[2];
  const float* wk  = (const float*)d_in[3];
  const float* bk  = (const float*)d_in[4];
  const float* wv  = (const float*)d_in[5];
  const float* bv  = (const float*)d_in[6];
  const float* wfc = (const float*)d_in[7];
  const float* bfc = (const float*)d_in[8];
  float* out = (float*)d_out;
  (void)in_sizes; (void)n_in; (void)out_size;

  hipFuncSetAttribute((const void*)k1_qkv,  hipFuncAttributeMaxDynamicSharedMemorySize, 48 * 1024);
  hipFuncSetAttribute((const void*)k2_attn, hipFuncAttributeMaxDynamicSharedMemorySize, 160 * 1024);
  hipFuncSetAttribute((const void*)k3_conv, hipFuncAttributeMaxDynamicSharedMemorySize, 64 * 1024);

  const size_t wb_bytes = 4 * 16384 * 2;          // 128 KB bf16 weights
  const size_t per_b = (size_t)16384 * 128 * 2;   // 4 MiB per array per b
  if (ws_size < wb_bytes + 4 * per_b) return;     // needs >= ~16.1 MB
  size_t nb_max = (ws_size - wb_bytes) / (4 * per_b);
  int nb = (int)(nb_max < 16 ? nb_max : 16);

  char* ws = (char*)d_ws;
  unsigned short* qws = (unsigned short*)(ws);
  unsigned short* kws = (unsigned short*)(ws + (size_t)nb * per_b);
  unsigned short* vws = (unsigned short*)(ws + (size_t)nb * per_b * 2);
  unsigned short* aws = (unsigned short*)(ws + (size_t)nb * per_b * 3);
  unsigned short* wb  = (unsigned short*)(ws + (size_t)nb * per_b * 4);

  k0_wcvt<<<dim3(64), dim3(256), 0, stream>>>(wq, wk, wv, wfc, wb);

  for (int b0 = 0; b0 < 16; b0 += nb) {
    int nbc = (16 - b0) < nb ? (16 - b0) : nb;
    k1_qkv<<<dim3(nbc * 128), dim3(512), 48 * 1024, stream>>>(
        rep, wb, bq, bk, bv, qws, kws, vws, b0);
    k2_attn<<<dim3(nbc * 64), dim3(1024), 160 * 1024, stream>>>(qws, kws, vws, aws);
    k3_conv<<<dim3(nbc * 64), dim3(512), 64 * 1024, stream>>>(aws, wb, bfc, out, b0);
  }
}